// Round 6
// baseline (227.259 us; speedup 1.0000x reference)
//
#include <hip/hip_runtime.h>
#include <stdint.h>

typedef __bf16 bf16_t;
typedef __bf16 bf16x8 __attribute__((ext_vector_type(8)));
typedef float f32x4 __attribute__((ext_vector_type(4)));

// async global->LDS, 16B per lane; LDS dest is wave-uniform base + lane*16
__device__ __forceinline__ void gload_lds16(const void* g, void* l) {
  __builtin_amdgcn_global_load_lds(
      (const __attribute__((address_space(1))) uint32_t*)g,
      (__attribute__((address_space(3))) uint32_t*)l, 16, 0, 0);
}

// ---------------- fused cast f32 -> bf16 for 3 buffers ----------------
__global__ void cast3_f32_bf16(const float* __restrict__ a, bf16_t* __restrict__ ao, int n4a,
                               const float* __restrict__ b, bf16_t* __restrict__ bo, int n4b,
                               const float* __restrict__ c, bf16_t* __restrict__ co, int n4c) {
  int i = blockIdx.x * blockDim.x + threadIdx.x;
  int stride = gridDim.x * blockDim.x;
  int total = n4a + n4b + n4c;
  for (int idx = i; idx < total; idx += stride) {
    const float* src; bf16_t* dst; int j = idx;
    if (j < n4a) { src = a; dst = ao; }
    else if ((j -= n4a) < n4b) { src = b; dst = bo; }
    else { j -= n4b; src = c; dst = co; }
    float4 v = reinterpret_cast<const float4*>(src)[j];
    union { bf16_t b[4]; uint2 u; } pk;
    pk.b[0] = (bf16_t)v.x; pk.b[1] = (bf16_t)v.y;
    pk.b[2] = (bf16_t)v.z; pk.b[3] = (bf16_t)v.w;
    reinterpret_cast<uint2*>(dst)[j] = pk.u;
  }
}

// ---------- pipelined GEMM: C = A * B^T (+bias), in-tile lgkm pipeline ------
// BM=BN=256, BK=32, K=1024 (NT=32). 8 waves (2M x 4N), wave tile 128x64 =
// 8x4 frags of 16x16x32 bf16 MFMA. 4-slot LDS ring (128KB), staged 3 ahead.
// Per tile (ONE barrier):
//   issue af0(4)+bfr(4) ds_reads | STAGE A,B(t+3) | issue af1(4) ds_reads
//   lgkmcnt(4) -> af0,bfr ready; MFMA0 x16 overlaps af1 data return
//   lgkmcnt(0) -> af1 ready;     MFMA1 x16
//   counted vmcnt (8 steady / 4,0 epilogue) ; s_barrier
// Safety: all 12 slot-t reads drained before the tile-end barrier, so tile
// t+1's stage-writes to slot(t-1) can't race; cross-wave staging visibility
// = every wave's vmcnt + the shared barrier. sched_barrier(0) after each
// inline-asm lgkmcnt (rule #18).
// LDS 16B-chunk swizzle: LDS[r][c] = G[r][c ^ ((r>>1)&3)] (both sides;
// verified 0 bank conflicts). Grid: XCD x owns bx slab [x*8,x*8+8), bx-fast.
template <bool BF16_OUT>
__global__ __launch_bounds__(512, 2)
void gemm_pipe(const bf16_t* __restrict__ A, const bf16_t* __restrict__ B,
               void* __restrict__ Cout, const float* __restrict__ bias,
               int N) {
  constexpr int K = 1024, NT = 32;
  __shared__ bf16_t Al[4][256 * 32];  // 4 x 16KB
  __shared__ bf16_t Bl[4][256 * 32];  // 4 x 16KB

  const int tid = threadIdx.x;
  const int l = tid & 63, w = tid >> 6;
  const int wm = w >> 2, wn = w & 3;

  const int bid = blockIdx.x;
  const int xcd = bid & 7;
  const int idx = bid >> 3;
  const int bx = xcd * 8 + (idx & 7);  // nbx = 64 (M = 16384)
  const int by = idx >> 3;
  const int m0 = bx * 256, n0 = by * 256;

  // staging: thread t: row = t>>2, lds chunk = t&3, global chunk (t&3)^((t>>3)&3)
  const int ra = tid >> 2;
  const int ca = ((tid & 3) ^ ((tid >> 3) & 3)) * 8;  // pre-swizzled k elems
  const bf16_t* pA0 = A + (size_t)(m0 +   0 + ra) * K + ca;
  const bf16_t* pA1 = A + (size_t)(m0 + 128 + ra) * K + ca;
  const bf16_t* pB0 = B + (size_t)(n0 +   0 + ra) * K + ca;
  const bf16_t* pB1 = B + (size_t)(n0 + 128 + ra) * K + ca;
  const int wb = w * 512;  // wave's 1KB segment (elems) within an 8KB issue

#define STAGE_A(t_, s_) do { const int kt_ = (t_) * 32;          \
    gload_lds16(pA0 + kt_, &Al[s_][wb]);                         \
    gload_lds16(pA1 + kt_, &Al[s_][4096 + wb]); } while (0)
#define STAGE_B(t_, s_) do { const int kt_ = (t_) * 32;          \
    gload_lds16(pB0 + kt_, &Bl[s_][wb]);                         \
    gload_lds16(pB1 + kt_, &Bl[s_][4096 + wb]); } while (0)

  // fragment reads: row = base + (l&15) + 16i -> (row>>1)&3 = (l>>1)&3
  const int abase = (wm * 128 + (l & 15)) * 32;
  const int bbase = (wn * 64 + (l & 15)) * 32;
  const int ck = ((l >> 4) ^ ((l >> 1) & 3)) * 8;  // swizzled k-chunk (elems)

  f32x4 acc[8][4] = {};

  STAGE_A(0, 0); STAGE_B(0, 0);
  STAGE_A(1, 1); STAGE_B(1, 1);
  STAGE_A(2, 2); STAGE_B(2, 2);
  asm volatile("s_waitcnt vmcnt(8)" ::: "memory");  // tile 0 landed
  __builtin_amdgcn_s_barrier();

  for (int t = 0; t < NT; ++t) {
    const int slot = t & 3;
    const int s3 = (t + 3) & 3;
    const bf16_t* As = Al[slot];
    const bf16_t* Bs = Bl[slot];
    bf16x8 af0[4], af1[4], bfr[4];

    // ---- issue all reads + stages up front ----
#pragma unroll
    for (int i = 0; i < 4; ++i)
      af0[i] = *reinterpret_cast<const bf16x8*>(&As[abase + i * 512 + ck]);
#pragma unroll
    for (int j = 0; j < 4; ++j)
      bfr[j] = *reinterpret_cast<const bf16x8*>(&Bs[bbase + j * 512 + ck]);
    if (t + 3 < NT) { STAGE_A(t + 3, s3); STAGE_B(t + 3, s3); }
#pragma unroll
    for (int i = 0; i < 4; ++i)
      af1[i] = *reinterpret_cast<const bf16x8*>(&As[abase + (i + 4) * 512 + ck]);

    // ---- MFMA0 overlaps af1 data return ----
    asm volatile("s_waitcnt lgkmcnt(4)" ::: "memory");
    __builtin_amdgcn_sched_barrier(0);
    __builtin_amdgcn_s_setprio(1);
#pragma unroll
    for (int i = 0; i < 4; ++i)
#pragma unroll
      for (int j = 0; j < 4; ++j)
        acc[i][j] = __builtin_amdgcn_mfma_f32_16x16x32_bf16(af0[i], bfr[j],
                                                            acc[i][j], 0, 0, 0);
    __builtin_amdgcn_s_setprio(0);

    asm volatile("s_waitcnt lgkmcnt(0)" ::: "memory");
    __builtin_amdgcn_sched_barrier(0);
    __builtin_amdgcn_s_setprio(1);
#pragma unroll
    for (int i = 0; i < 4; ++i)
#pragma unroll
      for (int j = 0; j < 4; ++j)
        acc[i + 4][j] = __builtin_amdgcn_mfma_f32_16x16x32_bf16(af1[i], bfr[j],
                                                                acc[i + 4][j], 0, 0, 0);
    __builtin_amdgcn_s_setprio(0);

    // counted vmcnt once per K-tile; drain only in final tiles
    if (t + 3 < NT)       asm volatile("s_waitcnt vmcnt(8)" ::: "memory");
    else if (t == NT - 3) asm volatile("s_waitcnt vmcnt(4)" ::: "memory");
    else if (t == NT - 2) asm volatile("s_waitcnt vmcnt(0)" ::: "memory");
    __builtin_amdgcn_s_barrier();
  }
#undef STAGE_A
#undef STAGE_B

  // ---- epilogue: C/D layout col = lane&15, row = (lane>>4)*4 + reg ----
  const int r0 = m0 + wm * 128 + (l >> 4) * 4;
  const int c0 = n0 + wn * 64 + (l & 15);
  if (BF16_OUT) {
    bf16_t* C = (bf16_t*)Cout;
#pragma unroll
    for (int i = 0; i < 8; ++i)
#pragma unroll
      for (int j = 0; j < 4; ++j)
#pragma unroll
        for (int r = 0; r < 4; ++r)
          C[(size_t)(r0 + i * 16 + r) * N + (c0 + j * 16)] = (bf16_t)acc[i][j][r];
  } else {
    float* C = (float*)Cout;
#pragma unroll
    for (int i = 0; i < 8; ++i)
#pragma unroll
      for (int j = 0; j < 4; ++j)
#pragma unroll
        for (int r = 0; r < 4; ++r)
          C[(size_t)(r0 + i * 16 + r) * N + (c0 + j * 16)] =
              acc[i][j][r] + bias[c0 + j * 16];
  }
}

// ---------------- per-token head-attention ----------------
__global__ __launch_bounds__(256)
void attn_heads(const bf16_t* __restrict__ qkv, bf16_t* __restrict__ out) {
  __shared__ float s[4][3072];
  const int w = threadIdx.x >> 6, l = threadIdx.x & 63;
  const size_t t = (size_t)blockIdx.x * 4 + w;
  const bf16_t* src = qkv + t * 3072;
#pragma unroll
  for (int i = 0; i < 6; ++i) {
    int f = (i * 64 + l) * 8;
    bf16x8 v = *reinterpret_cast<const bf16x8*>(&src[f]);
#pragma unroll
    for (int jj = 0; jj < 8; ++jj) s[w][f + jj] = (float)v[jj];
  }
  __syncthreads();

  const int h = l >> 2, ss = l & 3;
  float qr[16];
  const float* qb = &s[w][h * 192 + ss * 16];
#pragma unroll
  for (int d = 0; d < 16; ++d) qr[d] = qb[d];

  float sc[16];
#pragma unroll
  for (int g = 0; g < 16; ++g) {
    const float* kk = &s[w][g * 192 + 64 + ss * 16];
    float p = 0.f;
#pragma unroll
    for (int d = 0; d < 16; ++d) p += qr[d] * kk[d];
    p += __shfl_xor(p, 1);
    p += __shfl_xor(p, 2);
    sc[g] = p * 0.125f;
  }
  float m = sc[0];
#pragma unroll
  for (int g = 1; g < 16; ++g) m = fmaxf(m, sc[g]);
  float sum = 0.f;
#pragma unroll
  for (int g = 0; g < 16; ++g) { sc[g] = __expf(sc[g] - m); sum += sc[g]; }
  float inv = 1.f / sum;

  float o[16] = {};
#pragma unroll
  for (int g = 0; g < 16; ++g) {
    float a = sc[g] * inv;
    const float* vv = &s[w][g * 192 + 128 + ss * 16];
#pragma unroll
    for (int d = 0; d < 16; ++d) o[d] += a * vv[d];
  }
  union { bf16_t b[16]; uint4 u[2]; } pk;
#pragma unroll
  for (int d = 0; d < 16; ++d) pk.b[d] = (bf16_t)o[d];
  uint4* dst = reinterpret_cast<uint4*>(out + t * 1024 + h * 64 + ss * 16);
  dst[0] = pk.u[0];
  dst[1] = pk.u[1];
}

// ---------------- launch ----------------
extern "C" void kernel_launch(void* const* d_in, const int* in_sizes, int n_in,
                              void* d_out, int out_size, void* d_ws, size_t ws_size,
                              hipStream_t stream) {
  const float* x     = (const float*)d_in[0];  // [8,2048,1024]
  const float* Wqkv  = (const float*)d_in[1];  // [3072,1024]
  const float* Wproj = (const float*)d_in[2];  // [1024,1024]
  const float* bproj = (const float*)d_in[3];  // [1024]
  float* out = (float*)d_out;

  const int M = 8 * 2048;   // 16384 tokens -> 64 bx blocks of 256
  const int DM = 1024;
  const int F = 3072;

  char* ws = (char*)d_ws;
  bf16_t* xb     = (bf16_t*)ws;  ws += (size_t)M * DM * 2;
  bf16_t* wqkvb  = (bf16_t*)ws;  ws += (size_t)F * DM * 2;
  bf16_t* wprojb = (bf16_t*)ws;  ws += (size_t)DM * DM * 2;
  bf16_t* qkvb   = (bf16_t*)ws;  ws += (size_t)M * F * 2;
  bf16_t* attnb  = (bf16_t*)ws;

  cast3_f32_bf16<<<2048, 256, 0, stream>>>(x, xb, M * DM / 4,
                                           Wqkv, wqkvb, F * DM / 4,
                                           Wproj, wprojb, DM * DM / 4);

  // GEMM1: [16384,1024] x [3072,1024]^T -> bf16 [16384,3072]
  gemm_pipe<true><<<(M / 256) * (F / 256), 512, 0, stream>>>(
      xb, wqkvb, (void*)qkvb, nullptr, F);

  attn_heads<<<M / 4, 256, 0, stream>>>(qkvb, attnb);

  // GEMM2: [16384,1024] x [1024,1024]^T -> f32 [16384,1024] + bias
  gemm_pipe<false><<<(M / 256) * (DM / 256), 512, 0, stream>>>(
      attnb, wprojb, (void*)out, bproj, DM);
}

// Round 7
// 216.149 us; speedup vs baseline: 1.0514x; 1.0514x over previous
//
#include <hip/hip_runtime.h>
#include <stdint.h>

typedef __bf16 bf16_t;
typedef __bf16 bf16x8 __attribute__((ext_vector_type(8)));
typedef float f32x4 __attribute__((ext_vector_type(4)));

// async global->LDS, 16B per lane; LDS dest is wave-uniform base + lane*16
__device__ __forceinline__ void gload_lds16(const void* g, void* l) {
  __builtin_amdgcn_global_load_lds(
      (const __attribute__((address_space(1))) uint32_t*)g,
      (__attribute__((address_space(3))) uint32_t*)l, 16, 0, 0);
}

// ---------------- fused cast f32 -> bf16 for 3 buffers ----------------
__global__ void cast3_f32_bf16(const float* __restrict__ a, bf16_t* __restrict__ ao, int n4a,
                               const float* __restrict__ b, bf16_t* __restrict__ bo, int n4b,
                               const float* __restrict__ c, bf16_t* __restrict__ co, int n4c) {
  int i = blockIdx.x * blockDim.x + threadIdx.x;
  int stride = gridDim.x * blockDim.x;
  int total = n4a + n4b + n4c;
  for (int idx = i; idx < total; idx += stride) {
    const float* src; bf16_t* dst; int j = idx;
    if (j < n4a) { src = a; dst = ao; }
    else if ((j -= n4a) < n4b) { src = b; dst = bo; }
    else { j -= n4b; src = c; dst = co; }
    float4 v = reinterpret_cast<const float4*>(src)[j];
    union { bf16_t b[4]; uint2 u; } pk;
    pk.b[0] = (bf16_t)v.x; pk.b[1] = (bf16_t)v.y;
    pk.b[2] = (bf16_t)v.z; pk.b[3] = (bf16_t)v.w;
    reinterpret_cast<uint2*>(dst)[j] = pk.u;
  }
}

// ---------- pipelined GEMM: C = A * B^T (+bias), 2 blocks/CU overlap --------
// BM=256 BN=128 BK=32, K=1024 (NT=32). 256 threads = 4 waves (2M x 2N),
// wave tile 128x64 = 8x4 frags of 16x16x32 bf16 MFMA (r4-proven geometry).
// 3-slot LDS ring (72KB -> TWO blocks/CU; cross-block de-phasing overlaps
// one block's MFMA with the other's LDS reads - breaks the 1-block lockstep
// that capped MfmaUtil at 35%). Staged 2 ahead, 6 gload_lds per stage;
// steady s_waitcnt vmcnt(6), drain only at t=NT-2. r4's 2-phase rhythm:
//   P0: read af0[4]+bfr[4] | stage 3 loads(t+2) | bar | lgkm0 | 16 MFMA | bar
//   P1: read af1[4]        | stage 3 loads(t+2) | bar | lgkm0 | 16 MFMA
//       | vmcnt(6 / 0 at NT-2) | bar
// LDS 16B-chunk swizzle: LDS[r][c] = G[r][c ^ ((r>>1)&3)] (both sides;
// verified 0 bank conflicts). Grid: XCD x owns bx slab [x*8,x*8+8), bx-fast.
template <bool BF16_OUT>
__global__ __launch_bounds__(256, 2)
void gemm_pipe(const bf16_t* __restrict__ A, const bf16_t* __restrict__ B,
               void* __restrict__ Cout, const float* __restrict__ bias,
               int N) {
  constexpr int K = 1024, NT = 32;
  __shared__ bf16_t Al[3][256 * 32];  // 3 x 16KB
  __shared__ bf16_t Bl[3][128 * 32];  // 3 x 8KB

  const int tid = threadIdx.x;
  const int l = tid & 63, w = tid >> 6;
  const int wm = w >> 1, wn = w & 1;

  const int bid = blockIdx.x;
  const int xcd = bid & 7;
  const int idx = bid >> 3;
  const int bx = xcd * 8 + (idx & 7);  // nbx = 64 (M = 16384)
  const int by = idx >> 3;
  const int m0 = bx * 256, n0 = by * 128;

  // staging (256 threads, 4KB = 64 rows per issue): thread t: row = t>>2 + 64i,
  // lds chunk = t&3, global chunk = (t&3) ^ ((row>>1)&3) = (t&3)^((t>>3)&3)
  const int ra = tid >> 2;                            // 0..63
  const int ca = ((tid & 3) ^ ((tid >> 3) & 3)) * 8;  // pre-swizzled k elems
  const bf16_t* pA0 = A + (size_t)(m0 +   0 + ra) * K + ca;
  const bf16_t* pA1 = A + (size_t)(m0 +  64 + ra) * K + ca;
  const bf16_t* pA2 = A + (size_t)(m0 + 128 + ra) * K + ca;
  const bf16_t* pA3 = A + (size_t)(m0 + 192 + ra) * K + ca;
  const bf16_t* pB0 = B + (size_t)(n0 +   0 + ra) * K + ca;
  const bf16_t* pB1 = B + (size_t)(n0 +  64 + ra) * K + ca;
  const int wb = tid * 8;  // thread's 16B (8 elems) within a 4KB issue

#define STAGE_P0(t_, s_) do { const int kt_ = (t_) * 32;         \
    gload_lds16(pA0 + kt_, &Al[s_][0 * 2048 + wb]);              \
    gload_lds16(pA1 + kt_, &Al[s_][1 * 2048 + wb]);              \
    gload_lds16(pA2 + kt_, &Al[s_][2 * 2048 + wb]); } while (0)
#define STAGE_P1(t_, s_) do { const int kt_ = (t_) * 32;         \
    gload_lds16(pA3 + kt_, &Al[s_][3 * 2048 + wb]);              \
    gload_lds16(pB0 + kt_, &Bl[s_][0 * 2048 + wb]);              \
    gload_lds16(pB1 + kt_, &Bl[s_][1 * 2048 + wb]); } while (0)

  // fragment reads: row = base + (l&15) + 16i -> (row>>1)&3 = (l>>1)&3
  const int abase = (wm * 128 + (l & 15)) * 32;
  const int bbase = (wn * 64 + (l & 15)) * 32;
  const int ck = ((l >> 4) ^ ((l >> 1) & 3)) * 8;  // swizzled k-chunk (elems)

  f32x4 acc[8][4] = {};

  STAGE_P0(0, 0); STAGE_P1(0, 0);
  STAGE_P0(1, 1); STAGE_P1(1, 1);
  asm volatile("s_waitcnt vmcnt(6)" ::: "memory");  // tile 0 landed
  __builtin_amdgcn_s_barrier();

  int slot = 0;
  for (int t = 0; t < NT; ++t) {
    int s2 = slot + 2; if (s2 >= 3) s2 -= 3;
    const bf16_t* As = Al[slot];
    const bf16_t* Bs = Bl[slot];
    bf16x8 af0[4], af1[4], bfr[4];

    // -------- phase 0 --------
#pragma unroll
    for (int i = 0; i < 4; ++i)
      af0[i] = *reinterpret_cast<const bf16x8*>(&As[abase + i * 512 + ck]);
#pragma unroll
    for (int j = 0; j < 4; ++j)
      bfr[j] = *reinterpret_cast<const bf16x8*>(&Bs[bbase + j * 512 + ck]);
    if (t + 2 < NT) STAGE_P0(t + 2, s2);  // slot(t-1): reads drained last tile
    __builtin_amdgcn_s_barrier();
    asm volatile("s_waitcnt lgkmcnt(0)" ::: "memory");
    __builtin_amdgcn_sched_barrier(0);
    __builtin_amdgcn_s_setprio(1);
#pragma unroll
    for (int i = 0; i < 4; ++i)
#pragma unroll
      for (int j = 0; j < 4; ++j)
        acc[i][j] = __builtin_amdgcn_mfma_f32_16x16x32_bf16(af0[i], bfr[j],
                                                            acc[i][j], 0, 0, 0);
    __builtin_amdgcn_s_setprio(0);
    __builtin_amdgcn_s_barrier();

    // -------- phase 1 --------
#pragma unroll
    for (int i = 0; i < 4; ++i)
      af1[i] = *reinterpret_cast<const bf16x8*>(&As[abase + (i + 4) * 512 + ck]);
    if (t + 2 < NT) STAGE_P1(t + 2, s2);
    __builtin_amdgcn_s_barrier();
    asm volatile("s_waitcnt lgkmcnt(0)" ::: "memory");
    __builtin_amdgcn_sched_barrier(0);
    __builtin_amdgcn_s_setprio(1);
#pragma unroll
    for (int i = 0; i < 4; ++i)
#pragma unroll
      for (int j = 0; j < 4; ++j)
        acc[i + 4][j] = __builtin_amdgcn_mfma_f32_16x16x32_bf16(af1[i], bfr[j],
                                                                acc[i + 4][j], 0, 0, 0);
    __builtin_amdgcn_s_setprio(0);
    // counted vmcnt: guarantee stage(t+1) landed (6 newer may fly)
    if (t + 2 < NT)       asm volatile("s_waitcnt vmcnt(6)" ::: "memory");
    else if (t == NT - 2) asm volatile("s_waitcnt vmcnt(0)" ::: "memory");
    __builtin_amdgcn_s_barrier();
    slot = (slot == 2) ? 0 : slot + 1;
  }
#undef STAGE_P0
#undef STAGE_P1

  // ---- epilogue: C/D layout col = lane&15, row = (lane>>4)*4 + reg ----
  const int r0 = m0 + wm * 128 + (l >> 4) * 4;
  const int c0 = n0 + wn * 64 + (l & 15);
  if (BF16_OUT) {
    bf16_t* C = (bf16_t*)Cout;
#pragma unroll
    for (int i = 0; i < 8; ++i)
#pragma unroll
      for (int j = 0; j < 4; ++j)
#pragma unroll
        for (int r = 0; r < 4; ++r)
          C[(size_t)(r0 + i * 16 + r) * N + (c0 + j * 16)] = (bf16_t)acc[i][j][r];
  } else {
    float* C = (float*)Cout;
#pragma unroll
    for (int i = 0; i < 8; ++i)
#pragma unroll
      for (int j = 0; j < 4; ++j)
#pragma unroll
        for (int r = 0; r < 4; ++r)
          C[(size_t)(r0 + i * 16 + r) * N + (c0 + j * 16)] =
              acc[i][j][r] + bias[c0 + j * 16];
  }
}

// ---------------- per-token head-attention ----------------
__global__ __launch_bounds__(256)
void attn_heads(const bf16_t* __restrict__ qkv, bf16_t* __restrict__ out) {
  __shared__ float s[4][3072];
  const int w = threadIdx.x >> 6, l = threadIdx.x & 63;
  const size_t t = (size_t)blockIdx.x * 4 + w;
  const bf16_t* src = qkv + t * 3072;
#pragma unroll
  for (int i = 0; i < 6; ++i) {
    int f = (i * 64 + l) * 8;
    bf16x8 v = *reinterpret_cast<const bf16x8*>(&src[f]);
#pragma unroll
    for (int jj = 0; jj < 8; ++jj) s[w][f + jj] = (float)v[jj];
  }
  __syncthreads();

  const int h = l >> 2, ss = l & 3;
  float qr[16];
  const float* qb = &s[w][h * 192 + ss * 16];
#pragma unroll
  for (int d = 0; d < 16; ++d) qr[d] = qb[d];

  float sc[16];
#pragma unroll
  for (int g = 0; g < 16; ++g) {
    const float* kk = &s[w][g * 192 + 64 + ss * 16];
    float p = 0.f;
#pragma unroll
    for (int d = 0; d < 16; ++d) p += qr[d] * kk[d];
    p += __shfl_xor(p, 1);
    p += __shfl_xor(p, 2);
    sc[g] = p * 0.125f;
  }
  float m = sc[0];
#pragma unroll
  for (int g = 1; g < 16; ++g) m = fmaxf(m, sc[g]);
  float sum = 0.f;
#pragma unroll
  for (int g = 0; g < 16; ++g) { sc[g] = __expf(sc[g] - m); sum += sc[g]; }
  float inv = 1.f / sum;

  float o[16] = {};
#pragma unroll
  for (int g = 0; g < 16; ++g) {
    float a = sc[g] * inv;
    const float* vv = &s[w][g * 192 + 128 + ss * 16];
#pragma unroll
    for (int d = 0; d < 16; ++d) o[d] += a * vv[d];
  }
  union { bf16_t b[16]; uint4 u[2]; } pk;
#pragma unroll
  for (int d = 0; d < 16; ++d) pk.b[d] = (bf16_t)o[d];
  uint4* dst = reinterpret_cast<uint4*>(out + t * 1024 + h * 64 + ss * 16);
  dst[0] = pk.u[0];
  dst[1] = pk.u[1];
}

// ---------------- launch ----------------
extern "C" void kernel_launch(void* const* d_in, const int* in_sizes, int n_in,
                              void* d_out, int out_size, void* d_ws, size_t ws_size,
                              hipStream_t stream) {
  const float* x     = (const float*)d_in[0];  // [8,2048,1024]
  const float* Wqkv  = (const float*)d_in[1];  // [3072,1024]
  const float* Wproj = (const float*)d_in[2];  // [1024,1024]
  const float* bproj = (const float*)d_in[3];  // [1024]
  float* out = (float*)d_out;

  const int M = 8 * 2048;   // 16384 tokens -> 64 bx blocks of 256
  const int DM = 1024;
  const int F = 3072;

  char* ws = (char*)d_ws;
  bf16_t* xb     = (bf16_t*)ws;  ws += (size_t)M * DM * 2;
  bf16_t* wqkvb  = (bf16_t*)ws;  ws += (size_t)F * DM * 2;
  bf16_t* wprojb = (bf16_t*)ws;  ws += (size_t)DM * DM * 2;
  bf16_t* qkvb   = (bf16_t*)ws;  ws += (size_t)M * F * 2;
  bf16_t* attnb  = (bf16_t*)ws;

  cast3_f32_bf16<<<2048, 256, 0, stream>>>(x, xb, M * DM / 4,
                                           Wqkv, wqkvb, F * DM / 4,
                                           Wproj, wprojb, DM * DM / 4);

  // GEMM1: [16384,1024] x [3072,1024]^T -> bf16 [16384,3072]
  gemm_pipe<true><<<(M / 256) * (F / 128), 256, 0, stream>>>(
      xb, wqkvb, (void*)qkvb, nullptr, F);

  attn_heads<<<M / 4, 256, 0, stream>>>(qkvb, attnb);

  // GEMM2: [16384,1024] x [1024,1024]^T -> f32 [16384,1024] + bias
  gemm_pipe<false><<<(M / 256) * (DM / 128), 256, 0, stream>>>(
      attnb, wprojb, (void*)out, bproj, DM);
}

// Round 8
// 200.814 us; speedup vs baseline: 1.1317x; 1.0764x over previous
//
#include <hip/hip_runtime.h>
#include <stdint.h>

typedef __bf16 bf16_t;
typedef __bf16 bf16x8 __attribute__((ext_vector_type(8)));
typedef float f32x4 __attribute__((ext_vector_type(4)));

// async global->LDS, 16B per lane; HW dest = readfirstlane(ptr) + lane*16
__device__ __forceinline__ void gload_lds16(const void* g, void* l) {
  __builtin_amdgcn_global_load_lds(
      (const __attribute__((address_space(1))) uint32_t*)g,
      (__attribute__((address_space(3))) uint32_t*)l, 16, 0, 0);
}

// ---------------- fused cast f32 -> bf16 for 3 buffers ----------------
__global__ void cast3_f32_bf16(const float* __restrict__ a, bf16_t* __restrict__ ao, int n4a,
                               const float* __restrict__ b, bf16_t* __restrict__ bo, int n4b,
                               const float* __restrict__ c, bf16_t* __restrict__ co, int n4c) {
  int i = blockIdx.x * blockDim.x + threadIdx.x;
  int stride = gridDim.x * blockDim.x;
  int total = n4a + n4b + n4c;
  for (int idx = i; idx < total; idx += stride) {
    const float* src; bf16_t* dst; int j = idx;
    if (j < n4a) { src = a; dst = ao; }
    else if ((j -= n4a) < n4b) { src = b; dst = bo; }
    else { j -= n4b; src = c; dst = co; }
    float4 v = reinterpret_cast<const float4*>(src)[j];
    union { bf16_t b[4]; uint2 u; } pk;
    pk.b[0] = (bf16_t)v.x; pk.b[1] = (bf16_t)v.y;
    pk.b[2] = (bf16_t)v.z; pk.b[3] = (bf16_t)v.w;
    reinterpret_cast<uint2*>(dst)[j] = pk.u;
  }
}

// ---------- m201-style 8-phase GEMM: C[M][N] = A[M][K]*B[N][K]^T (+bias) ----
// BM=BN=256, BK=64, K=1024 (NT=16 K-tiles, NI=8 iters of 2 K-tiles).
// 512 thr = 8 waves (2M x 4N), wave tile 128x64; per phase: 16 MFMA quadrant.
// LDS: [2 dbuf][2 half(128 rows)] x (A,B) x 16KB = 128KB.
// Phase p: {ds_read quadrant | stage 1 half-tile (2 gload_lds)} bar
//          lgkm0 schedbar setprio(1) 16 MFMA setprio(0) bar
// Reads/phase {12,4,8,0}; stage map (audited vs last-read-of-half):
//   p1:A0(tb,d1) p2:A1(tb,d1) p3:B0(ta+2,d0) p4:B1(ta+2,d0)
//   p5:A0(ta+2,d0) p6:A1(ta+2,d0) p7:B0(tb+2,d1) p8:B1(tb+2,d1)
// vmcnt(2) at p4/p8 (6 worst-case outstanding; oldest 4 = next tile's halves);
// vmcnt(0) only at last iter p4. Swizzle for 128B rows: chunk ^= (row&7),
// both sides (pre-swizzled global src + swizzled ds_read) -> 2 lanes/bank.
// Grid: XCD x owns bx slab [x*8,x*8+8) (A-slab 4MB = its L2), bx-fast.
template <bool BF16_OUT>
__global__ __launch_bounds__(512, 2)
void gemm_8ph(const bf16_t* __restrict__ A, const bf16_t* __restrict__ B,
              void* __restrict__ Cout, const float* __restrict__ bias, int N) {
  constexpr int K = 1024, NI = 8;
  __shared__ bf16_t Al[2][2][128 * 64];
  __shared__ bf16_t Bl[2][2][128 * 64];

  const int tid = threadIdx.x;
  const int l = tid & 63, w = tid >> 6;
  const int wm = w >> 2, wn = w & 3;

  const int bid = blockIdx.x;
  const int xcd = bid & 7, idx = bid >> 3;
  const int bx = xcd * 8 + (idx & 7);  // nbx = 64 (M = 16384)
  const int by = idx >> 3;
  const int m0 = bx * 256, n0 = by * 256;

  // staging: thread t covers row (t>>3) of a 64-row issue, lds chunk t&7;
  // global chunk = (t&7) ^ (row&7) = (t&7) ^ ((t>>3)&7)  (inverse swizzle)
  const int srow = tid >> 3;
  const int sca = ((tid & 7) ^ (srow & 7)) * 8;
  const bf16_t* pA = A + (size_t)(m0 + srow) * K + sca;
  const bf16_t* pB = B + (size_t)(n0 + srow) * K + sca;

#define ST_A(t_, d_, h_) do {                                                         \
    gload_lds16(pA + (size_t)((h_) * 128) * K + (t_) * 64, &Al[d_][h_][tid * 8]);     \
    gload_lds16(pA + (size_t)((h_) * 128 + 64) * K + (t_) * 64,                       \
                &Al[d_][h_][4096 + tid * 8]); } while (0)
#define ST_B(t_, d_, h_) do {                                                         \
    gload_lds16(pB + (size_t)((h_) * 128) * K + (t_) * 64, &Bl[d_][h_][tid * 8]);     \
    gload_lds16(pB + (size_t)((h_) * 128 + 64) * K + (t_) * 64,                       \
                &Bl[d_][h_][4096 + tid * 8]); } while (0)

  // fragment reads: row = (l&15) + i*16 -> row&7 = l&7; k-step s: chunk s*4+(l>>4)
  const int arow = l & 15;
  const int brow = (wn & 1) * 64 + (l & 15);
  const int cks0 = (((l >> 4) + 0) ^ (l & 7)) * 8;
  const int cks1 = (((l >> 4) + 4) ^ (l & 7)) * 8;

#define LDA4(dst, base, i0) do {                                                      \
    _Pragma("unroll") for (int i = 0; i < 4; ++i) {                                   \
      dst[i][0] = *reinterpret_cast<const bf16x8*>(&base[(arow + (i0 + i) * 16) * 64 + cks0]); \
      dst[i][1] = *reinterpret_cast<const bf16x8*>(&base[(arow + (i0 + i) * 16) * 64 + cks1]); \
    } } while (0)
#define LDB2(dst, base, j0) do {                                                      \
    _Pragma("unroll") for (int j = 0; j < 2; ++j) {                                   \
      dst[j][0] = *reinterpret_cast<const bf16x8*>(&base[(brow + (j0 + j) * 16) * 64 + cks0]); \
      dst[j][1] = *reinterpret_cast<const bf16x8*>(&base[(brow + (j0 + j) * 16) * 64 + cks1]); \
    } } while (0)

#define MM16(afr, bfr, I0, J0)                                                        \
    __builtin_amdgcn_s_setprio(1);                                                    \
    _Pragma("unroll") for (int i = 0; i < 4; ++i)                                     \
    _Pragma("unroll") for (int j = 0; j < 2; ++j)                                     \
    _Pragma("unroll") for (int s = 0; s < 2; ++s)                                     \
      acc[I0 + i][J0 + j] = __builtin_amdgcn_mfma_f32_16x16x32_bf16(                  \
          afr[i][s], bfr[j][s], acc[I0 + i][J0 + j], 0, 0, 0);                        \
    __builtin_amdgcn_s_setprio(0);

#define BAR()    __builtin_amdgcn_s_barrier()
#define LGKM0()  do { asm volatile("s_waitcnt lgkmcnt(0)" ::: "memory");              \
                      __builtin_amdgcn_sched_barrier(0); } while (0)

  f32x4 acc[8][4] = {};

  // prologue: tile0 full + tile1 B-halves (12 loads); tile0 = oldest 8
  ST_A(0, 0, 0); ST_A(0, 0, 1); ST_B(0, 0, 0); ST_B(0, 0, 1);
  ST_B(1, 1, 0); ST_B(1, 1, 1);
  asm volatile("s_waitcnt vmcnt(4)" ::: "memory");
  BAR();

  for (int it = 0; it < NI; ++it) {
    const bool last = (it == NI - 1);
    const int ta = 2 * it, tb = ta + 1;
    const bf16_t* As0 = &Al[0][wm][0];
    const bf16_t* Bs0 = &Bl[0][wn >> 1][0];
    const bf16_t* As1 = &Al[1][wm][0];
    const bf16_t* Bs1 = &Bl[1][wn >> 1][0];
    bf16x8 af0[4][2], af1[4][2], bf0[2][2], bf1[2][2];

    // ---- P1: read af0-3 + bf0-1 (dbuf0) | stage A0(tb)->d1 ----
    LDA4(af0, As0, 0); LDB2(bf0, Bs0, 0);
    ST_A(tb, 1, 0);
    asm volatile("s_waitcnt lgkmcnt(8)" ::: "memory");
    BAR(); LGKM0();
    MM16(af0, bf0, 0, 0);
    BAR();
    // ---- P2: read bf2-3 | stage A1(tb)->d1 ----
    LDB2(bf1, Bs0, 2);
    ST_A(tb, 1, 1);
    BAR(); LGKM0();
    MM16(af0, bf1, 0, 2);
    BAR();
    // ---- P3: read af4-7 | stage B0(ta+2)->d0 ----
    LDA4(af1, As0, 4);
    if (!last) ST_B(ta + 2, 0, 0);
    BAR(); LGKM0();
    MM16(af1, bf0, 4, 0);
    BAR();
    // ---- P4: no reads | stage B1(ta+2)->d0 | vmcnt gate for tile tb ----
    if (!last) ST_B(ta + 2, 0, 1);
    BAR();
    MM16(af1, bf1, 4, 2);
    if (last) asm volatile("s_waitcnt vmcnt(0)" ::: "memory");
    else      asm volatile("s_waitcnt vmcnt(2)" ::: "memory");
    BAR();

    // ---- P5: read af0-3 + bf0-1 (dbuf1) | stage A0(ta+2)->d0 ----
    LDA4(af0, As1, 0); LDB2(bf0, Bs1, 0);
    if (!last) ST_A(ta + 2, 0, 0);
    asm volatile("s_waitcnt lgkmcnt(8)" ::: "memory");
    BAR(); LGKM0();
    MM16(af0, bf0, 0, 0);
    BAR();
    // ---- P6: read bf2-3 | stage A1(ta+2)->d0 ----
    LDB2(bf1, Bs1, 2);
    if (!last) ST_A(ta + 2, 0, 1);
    BAR(); LGKM0();
    MM16(af0, bf1, 0, 2);
    BAR();
    // ---- P7: read af4-7 | stage B0(tb+2)->d1 ----
    LDA4(af1, As1, 4);
    if (!last) ST_B(tb + 2, 1, 0);
    BAR(); LGKM0();
    MM16(af1, bf0, 4, 0);
    BAR();
    // ---- P8: no reads | stage B1(tb+2)->d1 | vmcnt gate for tile ta+2 ----
    if (!last) ST_B(tb + 2, 1, 1);
    BAR();
    MM16(af1, bf1, 4, 2);
    if (!last) asm volatile("s_waitcnt vmcnt(2)" ::: "memory");
    BAR();
  }
#undef ST_A
#undef ST_B
#undef LDA4
#undef LDB2
#undef MM16
#undef BAR
#undef LGKM0

  // ---- epilogue: C/D layout col = lane&15, row = (lane>>4)*4 + reg ----
  const int r0 = m0 + wm * 128 + (l >> 4) * 4;
  const int c0 = n0 + wn * 64 + (l & 15);
  if (BF16_OUT) {
    bf16_t* C = (bf16_t*)Cout;
#pragma unroll
    for (int i = 0; i < 8; ++i)
#pragma unroll
      for (int j = 0; j < 4; ++j)
#pragma unroll
        for (int r = 0; r < 4; ++r)
          C[(size_t)(r0 + i * 16 + r) * N + (c0 + j * 16)] = (bf16_t)acc[i][j][r];
  } else {
    float* C = (float*)Cout;
#pragma unroll
    for (int i = 0; i < 8; ++i)
#pragma unroll
      for (int j = 0; j < 4; ++j)
#pragma unroll
        for (int r = 0; r < 4; ++r)
          C[(size_t)(r0 + i * 16 + r) * N + (c0 + j * 16)] =
              acc[i][j][r] + bias[c0 + j * 16];
  }
}

// ---------------- per-token head-attention ----------------
__global__ __launch_bounds__(256)
void attn_heads(const bf16_t* __restrict__ qkv, bf16_t* __restrict__ out) {
  __shared__ float s[4][3072];
  const int w = threadIdx.x >> 6, l = threadIdx.x & 63;
  const size_t t = (size_t)blockIdx.x * 4 + w;
  const bf16_t* src = qkv + t * 3072;
#pragma unroll
  for (int i = 0; i < 6; ++i) {
    int f = (i * 64 + l) * 8;
    bf16x8 v = *reinterpret_cast<const bf16x8*>(&src[f]);
#pragma unroll
    for (int jj = 0; jj < 8; ++jj) s[w][f + jj] = (float)v[jj];
  }
  __syncthreads();

  const int h = l >> 2, ss = l & 3;
  float qr[16];
  const float* qb = &s[w][h * 192 + ss * 16];
#pragma unroll
  for (int d = 0; d < 16; ++d) qr[d] = qb[d];

  float sc[16];
#pragma unroll
  for (int g = 0; g < 16; ++g) {
    const float* kk = &s[w][g * 192 + 64 + ss * 16];
    float p = 0.f;
#pragma unroll
    for (int d = 0; d < 16; ++d) p += qr[d] * kk[d];
    p += __shfl_xor(p, 1);
    p += __shfl_xor(p, 2);
    sc[g] = p * 0.125f;
  }
  float m = sc[0];
#pragma unroll
  for (int g = 1; g < 16; ++g) m = fmaxf(m, sc[g]);
  float sum = 0.f;
#pragma unroll
  for (int g = 0; g < 16; ++g) { sc[g] = __expf(sc[g] - m); sum += sc[g]; }
  float inv = 1.f / sum;

  float o[16] = {};
#pragma unroll
  for (int g = 0; g < 16; ++g) {
    float a = sc[g] * inv;
    const float* vv = &s[w][g * 192 + 128 + ss * 16];
#pragma unroll
    for (int d = 0; d < 16; ++d) o[d] += a * vv[d];
  }
  union { bf16_t b[16]; uint4 u[2]; } pk;
#pragma unroll
  for (int d = 0; d < 16; ++d) pk.b[d] = (bf16_t)o[d];
  uint4* dst = reinterpret_cast<uint4*>(out + t * 1024 + h * 64 + ss * 16);
  dst[0] = pk.u[0];
  dst[1] = pk.u[1];
}

// ---------------- launch ----------------
extern "C" void kernel_launch(void* const* d_in, const int* in_sizes, int n_in,
                              void* d_out, int out_size, void* d_ws, size_t ws_size,
                              hipStream_t stream) {
  const float* x     = (const float*)d_in[0];  // [8,2048,1024]
  const float* Wqkv  = (const float*)d_in[1];  // [3072,1024]
  const float* Wproj = (const float*)d_in[2];  // [1024,1024]
  const float* bproj = (const float*)d_in[3];  // [1024]
  float* out = (float*)d_out;

  const int M = 8 * 2048;   // 16384 tokens -> 64 bx blocks of 256
  const int DM = 1024;
  const int F = 3072;

  char* ws = (char*)d_ws;
  bf16_t* xb     = (bf16_t*)ws;  ws += (size_t)M * DM * 2;
  bf16_t* wqkvb  = (bf16_t*)ws;  ws += (size_t)F * DM * 2;
  bf16_t* wprojb = (bf16_t*)ws;  ws += (size_t)DM * DM * 2;
  bf16_t* qkvb   = (bf16_t*)ws;  ws += (size_t)M * F * 2;
  bf16_t* attnb  = (bf16_t*)ws;

  cast3_f32_bf16<<<2048, 256, 0, stream>>>(x, xb, M * DM / 4,
                                           Wqkv, wqkvb, F * DM / 4,
                                           Wproj, wprojb, DM * DM / 4);

  // GEMM1: [16384,1024] x [3072,1024]^T -> bf16 [16384,3072]
  gemm_8ph<true><<<(M / 256) * (F / 256), 512, 0, stream>>>(
      xb, wqkvb, (void*)qkvb, nullptr, F);

  attn_heads<<<M / 4, 256, 0, stream>>>(qkvb, attnb);

  // GEMM2: [16384,1024] x [1024,1024]^T -> f32 [16384,1024] + bias
  gemm_8ph<false><<<(M / 256) * (DM / 256), 512, 0, stream>>>(
      attnb, wprojb, (void*)out, bproj, DM);
}